// Round 6
// baseline (1182.263 us; speedup 1.0000x reference)
//
#include <hip/hip_runtime.h>

#define N_NODES 50000
#define M_PAD 50048      // N_NODES rounded up to 128
#define N_EDGES 500000
#define HEADS 6
#define CH 64
#define F_HID 384
#define IN_DIM 131
#define K0PAD 160        // layer-0 K padded to multiple of 32
#define CAP 64           // edge chunk per node
#define NBM 391          // cdiv(N_NODES,128)

static inline int cdiv(int a, int b) { return (a + b - 1) / b; }

typedef __attribute__((ext_vector_type(8))) __bf16 bf16x8;
typedef __attribute__((ext_vector_type(4))) float f32x4;
typedef __attribute__((ext_vector_type(8))) unsigned short us8;
typedef __attribute__((ext_vector_type(4))) unsigned short us4;
typedef __attribute__((ext_vector_type(4))) _Float16 f16x4;

// round-to-nearest-even fp32 -> bf16 split: v ~= hi + lo
__device__ __forceinline__ void bsplit(float v, unsigned short& h, unsigned short& l) {
  unsigned u = __builtin_bit_cast(unsigned, v);
  unsigned hr = (u + 0x7FFFu + ((u >> 16) & 1u)) >> 16;
  h = (unsigned short)hr;
  float hf = __builtin_bit_cast(float, hr << 16);
  float r = v - hf;
  unsigned u2 = __builtin_bit_cast(unsigned, r);
  unsigned lr = (u2 + 0x7FFFu + ((u2 >> 16) & 1u)) >> 16;
  l = (unsigned short)lr;
}

__device__ __forceinline__ void gload16(const void* g, void* lds) {
  __builtin_amdgcn_global_load_lds((const __attribute__((address_space(1))) void*)g,
                                   (__attribute__((address_space(3))) void*)lds, 16, 0, 0);
}

// ---------------- CSR build ----------------
__global__ void count_kernel(const int* __restrict__ ei, int* __restrict__ deg) {
  int e = blockIdx.x * blockDim.x + threadIdx.x;
  if (e < N_EDGES) atomicAdd(&deg[ei[N_EDGES + e]], 1);
}

__global__ void scan_kernel(const int* __restrict__ deg, int* __restrict__ off) {
  __shared__ int sdata[256];
  int tid = threadIdx.x;
  int carry = 0;
  if (tid == 0) off[0] = 0;
  for (int base = 0; base < N_NODES; base += 1024) {
    int idx0 = base + tid * 4;
    int v[4]; int s = 0;
#pragma unroll
    for (int j = 0; j < 4; j++) {
      v[j] = (idx0 + j < N_NODES) ? deg[idx0 + j] : 0;
      s += v[j];
    }
    sdata[tid] = s;
    __syncthreads();
    for (int o = 1; o < 256; o <<= 1) {
      int x = (tid >= o) ? sdata[tid - o] : 0;
      __syncthreads();
      sdata[tid] += x;
      __syncthreads();
    }
    int excl = sdata[tid] - s + carry;
    int total = sdata[255];
    int run = excl;
#pragma unroll
    for (int j = 0; j < 4; j++) {
      run += v[j];
      if (idx0 + j < N_NODES) off[idx0 + j + 1] = run;
    }
    carry += total;
    __syncthreads();
  }
}

__global__ void scatter_kernel(const int* __restrict__ ei, int* __restrict__ cursor,
                               int* __restrict__ csr_src) {
  int e = blockIdx.x * blockDim.x + threadIdx.x;
  if (e < N_EDGES) {
    int d = ei[N_EDGES + e];
    int p = atomicAdd(&cursor[d], 1);
    csr_src[p] = ei[e];
  }
}

// ---------------- packers ----------------
__global__ void convert_x(const float* __restrict__ x, unsigned short* __restrict__ xp) {
  int t = blockIdx.x * blockDim.x + threadIdx.x;
  const int npc = K0PAD / 8;
  if (t >= M_PAD * npc) return;
  int r = t / npc, g = t % npc;
  int kt = g >> 2, kb = g & 3;
  int k0 = kt * 32 + kb * 8;
  us8 hv, lv;
#pragma unroll
  for (int j = 0; j < 8; j++) {
    int k = k0 + j;
    float v = (r < N_NODES && k < IN_DIM) ? x[(long)r * IN_DIM + k] : 0.0f;
    unsigned short h, l; bsplit(v, h, l);
    hv[j] = h; lv[j] = l;
  }
  char* base = (char*)xp + (size_t)r * (4 * K0PAD) + kt * 128;
  int x7 = r & 7;
  *(us8*)(base + (((2 * kb) ^ x7) << 4)) = hv;
  *(us8*)(base + (((2 * kb + 1) ^ x7) << 4)) = lv;
}

__global__ void convert_W(const float* __restrict__ W, unsigned short* __restrict__ Wt,
                          int Kreal, int Kpad) {
  int t = blockIdx.x * blockDim.x + threadIdx.x;
  int npc = Kpad >> 3;
  if (t >= F_HID * npc) return;
  int n = t / npc, g = t % npc;
  int kt = g >> 2, kb = g & 3;
  int k0 = kt * 32 + kb * 8;
  us8 hv, lv;
#pragma unroll
  for (int j = 0; j < 8; j++) {
    int k = k0 + j;
    float v = (k < Kreal) ? W[(long)k * F_HID + n] : 0.0f;
    unsigned short h, l; bsplit(v, h, l);
    hv[j] = h; lv[j] = l;
  }
  char* base = (char*)Wt + (size_t)n * (4 * Kpad) + kt * 128;
  int x7 = n & 7;
  *(us8*)(base + (((2 * kb) ^ x7) << 4)) = hv;
  *(us8*)(base + (((2 * kb + 1) ^ x7) << 4)) = lv;
}

// ---------------- va precompute: va[l][k][j] = sum_c W_l[k, h*64+c] * a[h][c] ----------
// j in [0,12): j<6 -> a_src head j; j>=6 -> a_dst head j-6. Layer 0 rows k>=131 are 0.
__global__ void va_kernel(const float* __restrict__ W0, const float* __restrict__ W1,
                          const float* __restrict__ W2, const float* __restrict__ W3,
                          const float* __restrict__ as0, const float* __restrict__ ad0,
                          const float* __restrict__ as1, const float* __restrict__ ad1,
                          const float* __restrict__ as2, const float* __restrict__ ad2,
                          const float* __restrict__ as3, const float* __restrict__ ad3,
                          float* __restrict__ va) {
  int t = blockIdx.x * blockDim.x + threadIdx.x;
  if (t >= 4 * F_HID * 12) return;
  int l = t / (F_HID * 12);
  int rem = t - l * (F_HID * 12);
  int k = rem / 12, j = rem % 12;
  int h = j % 6;
  const float* Wl = l == 0 ? W0 : (l == 1 ? W1 : (l == 2 ? W2 : W3));
  const float* al = (j < 6) ? (l == 0 ? as0 : (l == 1 ? as1 : (l == 2 ? as2 : as3)))
                            : (l == 0 ? ad0 : (l == 1 ? ad1 : (l == 2 ? ad2 : ad3)));
  float acc = 0.0f;
  if (!(l == 0 && k >= IN_DIM)) {
    const float* wrow = Wl + (size_t)k * F_HID + h * CH;
    const float* arow = al + h * CH;
#pragma unroll 8
    for (int c = 0; c < CH; ++c) acc += wrow[c] * arow[c];
  }
  va[t] = acc;
}

// ---------------- layer-0 attention logits straight from x ----------------
// al_s[n,h] = sum_k x[n,k] * va0[k][h]  (4 nodes/block x 64 lanes)
__global__ __launch_bounds__(256) void al0_kernel(const float* __restrict__ x,
                                                  const float* __restrict__ va,
                                                  float* __restrict__ als,
                                                  float* __restrict__ ald) {
  __shared__ float va0L[IN_DIM * 12];
  int tid = threadIdx.x;
  for (int i = tid; i < IN_DIM * 12; i += 256) va0L[i] = va[i];
  __syncthreads();
  int sub = tid >> 6, lane = tid & 63;
  int n = blockIdx.x * 4 + sub;
  float acc[12];
#pragma unroll
  for (int j = 0; j < 12; ++j) acc[j] = 0.0f;
  for (int k = lane; k < IN_DIM; k += 64) {
    float xv = x[(size_t)n * IN_DIM + k];
#pragma unroll
    for (int j = 0; j < 12; ++j) acc[j] += xv * va0L[k * 12 + j];
  }
#pragma unroll
  for (int o = 32; o; o >>= 1)
#pragma unroll
    for (int j = 0; j < 12; ++j) acc[j] += __shfl_xor(acc[j], o);
  if (lane < 6) als[n * 6 + lane] = acc[lane];
  else if (lane < 12) ald[n * 6 + lane - 6] = acc[lane];
}

// ---------------- split-bf16 MFMA GEMM, fp16 output, XCD-grouped swizzle ----------
template <int K>
__global__ __launch_bounds__(256) void gemm_mfma(const unsigned short* __restrict__ Ap,
                                                 const unsigned short* __restrict__ Bp,
                                                 _Float16* __restrict__ O) {
  constexpr int NKT = K / 32;
  constexpr size_t RB = 4 * K;
  __shared__ __align__(16) char smA[16384];
  __shared__ __align__(16) char smB[16384];
  // XCD-grouped: the 3 bn-siblings of one bm run consecutively on one XCD -> A L2-reuse
  int xcd = blockIdx.x & 7, slot = blockIdx.x >> 3;
  int bn = slot % 3, tt = slot / 3;
  int bm = tt * 8 + xcd;
  if (bm >= NBM) return;
  int row0 = bm * 128, col0 = bn * 128;
  int tid = threadIdx.x, lane = tid & 63, wv = tid >> 6;
  int wy = wv >> 1, wx = wv & 1;

  f32x4 acc[4][4];
#pragma unroll
  for (int i = 0; i < 4; i++)
#pragma unroll
    for (int j = 0; j < 4; j++) acc[i][j] = (f32x4)0.0f;

  const char* Ab = (const char*)Ap + (size_t)row0 * RB;
  const char* Bb = (const char*)Bp + (size_t)col0 * RB;

  int kb2 = (lane >> 4) * 2;
  int x7 = lane & 7;
  int rA = wy * 64 + (lane & 15);
  int rB = wx * 64 + (lane & 15);

  for (int kt = 0; kt < NKT; ++kt) {
#pragma unroll
    for (int i = 0; i < 4; ++i) {
      int b = wv * 4096 + i * 1024;
      int bl = b + lane * 16;
      int r = bl >> 7, q = bl & 127;
      gload16(Ab + (size_t)r * RB + kt * 128 + q, smA + b);
      gload16(Bb + (size_t)r * RB + kt * 128 + q, smB + b);
    }
    __syncthreads();

    bf16x8 ah[4], alo[4], bh[4], blo[4];
#pragma unroll
    for (int mf = 0; mf < 4; ++mf) {
      const char* p = smA + (rA + mf * 16) * 128;
      ah[mf]  = *(const bf16x8*)(p + ((kb2 ^ x7) << 4));
      alo[mf] = *(const bf16x8*)(p + (((kb2 + 1) ^ x7) << 4));
    }
#pragma unroll
    for (int nf = 0; nf < 4; ++nf) {
      const char* p = smB + (rB + nf * 16) * 128;
      bh[nf]  = *(const bf16x8*)(p + ((kb2 ^ x7) << 4));
      blo[nf] = *(const bf16x8*)(p + (((kb2 + 1) ^ x7) << 4));
    }
#pragma unroll
    for (int mf = 0; mf < 4; ++mf)
#pragma unroll
      for (int nf = 0; nf < 4; ++nf) {
        acc[mf][nf] = __builtin_amdgcn_mfma_f32_16x16x32_bf16(ah[mf], bh[nf], acc[mf][nf], 0, 0, 0);
        acc[mf][nf] = __builtin_amdgcn_mfma_f32_16x16x32_bf16(alo[mf], bh[nf], acc[mf][nf], 0, 0, 0);
        acc[mf][nf] = __builtin_amdgcn_mfma_f32_16x16x32_bf16(ah[mf], blo[nf], acc[mf][nf], 0, 0, 0);
      }
    __syncthreads();
  }

  int cr = (lane >> 4) * 4, cc = lane & 15;
#pragma unroll
  for (int mf = 0; mf < 4; ++mf)
#pragma unroll
    for (int r = 0; r < 4; ++r) {
      int row = row0 + wy * 64 + mf * 16 + cr + r;
      if (row < N_NODES) {
#pragma unroll
        for (int nf = 0; nf < 4; ++nf)
          O[(size_t)row * F_HID + col0 + wx * 64 + nf * 16 + cc] = (_Float16)acc[mf][nf][r];
      }
    }
}

// ---------------- phase-split agg core ----------------
#define AGG_CORE(FEAT, OFF, CSR, ALS, ALD)                                        \
  int tid = threadIdx.x;                                                          \
  int sub = tid / 96, t96 = tid - sub * 96;                                       \
  int nb = blockIdx.x * 4;                                                        \
  int n = nb + sub;                                                               \
  int c4 = t96 * 4, h = t96 >> 4;                                                 \
  int o_[5];                                                                      \
  _Pragma("unroll")                                                               \
  for (int k = 0; k < 5; ++k) o_[k] = OFF[nb + k];                                \
  int dmax = 0;                                                                   \
  _Pragma("unroll")                                                               \
  for (int k = 0; k < 4; ++k) dmax = max(dmax, o_[k + 1] - o_[k]);                \
  int nch = (dmax + CAP - 1) / CAP; if (nch < 1) nch = 1;                         \
  int s0 = o_[sub], deg = o_[sub + 1] - o_[sub];                                  \
  int bsub = tid / 6, bh = tid - bsub * 6;                                        \
  int bs0 = 0, bdeg = 0;                                                          \
  if (tid < 24) { bs0 = o_[bsub]; bdeg = o_[bsub + 1] - o_[bsub]; }               \
  (void)bs0;                                                                      \
  float m_run = -INFINITY, s_run = 0.0f;                                          \
  float a0 = 0, a1 = 0, a2 = 0, a3 = 0;                                           \
  for (int ch = 0; ch < nch; ++ch) {                                              \
    int base = ch * CAP;                                                          \
    int cl = deg - base; cl = cl < 0 ? 0 : (cl > CAP ? CAP : cl);                 \
    if (t96 < cl) lsrc[sub][t96] = CSR[s0 + base + t96];                          \
    for (int j = t96; j < cl * 6; j += 96) {                                      \
      int i = j / 6, hh = j - i * 6;                                              \
      int s = CSR[s0 + base + i];                                                 \
      float e = ALS[s * 6 + hh] + ALD[n * 6 + hh];                                \
      e = e > 0.0f ? e : 0.2f * e;                                                \
      lew[sub][hh][i] = e;                                                        \
    }                                                                             \
    __syncthreads();                                                              \
    if (tid < 24) {                                                               \
      int bcl = bdeg - base; bcl = bcl < 0 ? 0 : (bcl > CAP ? CAP : bcl);         \
      float asc;                                                                  \
      if (bcl > 0) {                                                              \
        float mc = -INFINITY;                                                     \
        for (int i = 0; i < bcl; ++i) mc = fmaxf(mc, lew[bsub][bh][i]);           \
        float mn = fmaxf(m_run, mc);                                              \
        asc = (m_run == -INFINITY) ? 0.0f : __expf(m_run - mn);                   \
        float sc = 0.0f;                                                          \
        for (int i = 0; i < bcl; ++i) {                                           \
          float wv = __expf(lew[bsub][bh][i] - mn);                               \
          lew[bsub][bh][i] = wv;                                                  \
          sc += wv;                                                               \
        }                                                                         \
        s_run = s_run * asc + sc;                                                 \
        m_run = mn;                                                               \
      } else asc = 1.0f;                                                          \
      lasc[bsub][bh] = asc;                                                       \
      if (ch == nch - 1) lrr[bsub][bh] = 1.0f / (s_run + 1e-16f);                 \
    }                                                                             \
    __syncthreads();                                                              \
    float cc0 = 0, cc1 = 0, cc2 = 0, cc3 = 0;                                     \
    for (int i = 0; i < cl; ++i) {                                                \
      int s = lsrc[sub][i];                                                       \
      float wv = lew[sub][h][i];                                                  \
      f16x4 fv = *(const f16x4*)(FEAT + (size_t)s * F_HID + c4);                  \
      cc0 += wv * (float)fv[0];                                                   \
      cc1 += wv * (float)fv[1];                                                   \
      cc2 += wv * (float)fv[2];                                                   \
      cc3 += wv * (float)fv[3];                                                   \
    }                                                                             \
    float asc2 = lasc[sub][h];                                                    \
    a0 = a0 * asc2 + cc0; a1 = a1 * asc2 + cc1;                                   \
    a2 = a2 * asc2 + cc2; a3 = a3 * asc2 + cc3;                                   \
    __syncthreads();                                                              \
  }                                                                               \
  float rr = lrr[sub][h];

// hidden layers: normalize + bias + ELU + split-bf16 pack + NEXT-layer al fused
__global__ __launch_bounds__(384) void agg_hidden(const _Float16* __restrict__ feat,
                                                  const int* __restrict__ off,
                                                  const int* __restrict__ csr_src,
                                                  const float* __restrict__ al_s,
                                                  const float* __restrict__ al_d,
                                                  const float* __restrict__ bias,
                                                  const float* __restrict__ va_next,
                                                  float* __restrict__ als_w,
                                                  float* __restrict__ ald_w,
                                                  unsigned short* __restrict__ Apk) {
  __shared__ int   lsrc[4][CAP + 1];
  __shared__ float lew[4][6][CAP + 1];
  __shared__ float lasc[4][6];
  __shared__ float lrr[4][6];
  __shared__ float vsL[F_HID * 12];     // va_next staged: [k][j]
  __shared__ float alred[4][12][96];
  // stage va_next (overlaps with first-chunk phase A; synced by loop barrier)
  for (int i = threadIdx.x; i < F_HID * 12; i += 384) vsL[i] = va_next[i];
  AGG_CORE(feat, off, csr_src, al_s, al_d)
  float v0 = a0 * rr + bias[c4 + 0];
  float v1 = a1 * rr + bias[c4 + 1];
  float v2 = a2 * rr + bias[c4 + 2];
  float v3 = a3 * rr + bias[c4 + 3];
  v0 = v0 > 0.0f ? v0 : (__expf(v0) - 1.0f);
  v1 = v1 > 0.0f ? v1 : (__expf(v1) - 1.0f);
  v2 = v2 > 0.0f ? v2 : (__expf(v2) - 1.0f);
  v3 = v3 > 0.0f ? v3 : (__expf(v3) - 1.0f);
  unsigned short h0, l0, h1, l1, h2, l2, h3, l3;
  bsplit(v0, h0, l0);
  bsplit(v1, h1, l1);
  bsplit(v2, h2, l2);
  bsplit(v3, h3, l3);
  us4 hv, lv;
  hv[0] = h0; hv[1] = h1; hv[2] = h2; hv[3] = h3;
  lv[0] = l0; lv[1] = l1; lv[2] = l2; lv[3] = l3;
  int kt = c4 >> 5, kb = (c4 >> 3) & 3, jb = (c4 & 7) * 2;
  char* basep = (char*)Apk + (size_t)n * (4 * F_HID) + kt * 128;
  int x7 = n & 7;
  *(us4*)(basep + (((2 * kb) ^ x7) << 4) + jb) = hv;
  *(us4*)(basep + (((2 * kb + 1) ^ x7) << 4) + jb) = lv;
  // ---- fused next-layer al: partial[j] = sum_i v_i * va_next[c4+i][j] ----
#pragma unroll
  for (int j = 0; j < 12; ++j) {
    float p = v0 * vsL[(c4 + 0) * 12 + j] + v1 * vsL[(c4 + 1) * 12 + j]
            + v2 * vsL[(c4 + 2) * 12 + j] + v3 * vsL[(c4 + 3) * 12 + j];
    alred[sub][j][t96] = p;
  }
  __syncthreads();
  // tree-reduce 96 -> 3 over all (sub, j) lanes
  for (int len = 96; len > 3; len >>= 1) {
    int half = len >> 1;
    for (int idx = threadIdx.x; idx < 4 * 12 * half; idx += 384) {
      int s2 = idx / (12 * half);
      int r2 = idx - s2 * (12 * half);
      int j2 = r2 / half, i2 = r2 - j2 * half;
      alred[s2][j2][i2] += alred[s2][j2][i2 + half];
    }
    __syncthreads();
  }
  if (threadIdx.x < 48) {
    int s2 = threadIdx.x / 12, j2 = threadIdx.x % 12;
    float al = alred[s2][j2][0] + alred[s2][j2][1] + alred[s2][j2][2];
    int nn = nb + s2;
    if (j2 < 6) als_w[nn * 6 + j2] = al;
    else        ald_w[nn * 6 + j2 - 6] = al;
  }
}

// output layer: normalize + head-mean + bias
__global__ __launch_bounds__(384) void agg_out(const _Float16* __restrict__ feat,
                                               const int* __restrict__ off,
                                               const int* __restrict__ csr_src,
                                               const float* __restrict__ al_s,
                                               const float* __restrict__ al_d,
                                               const float* __restrict__ b3,
                                               float* __restrict__ out) {
  __shared__ int   lsrc[4][CAP + 1];
  __shared__ float lew[4][6][CAP + 1];
  __shared__ float lasc[4][6];
  __shared__ float lrr[4][6];
  __shared__ float red[4][384];
  AGG_CORE(feat, off, csr_src, al_s, al_d)
  red[sub][c4 + 0] = a0 * rr;
  red[sub][c4 + 1] = a1 * rr;
  red[sub][c4 + 2] = a2 * rr;
  red[sub][c4 + 3] = a3 * rr;
  __syncthreads();
  if (t96 < 16) {
    int c = t96 * 4;
    f32x4 o = (f32x4)0.0f;
#pragma unroll
    for (int hh = 0; hh < HEADS; hh++) {
#pragma unroll
      for (int j = 0; j < 4; j++) o[j] += red[sub][hh * CH + c + j];
    }
#pragma unroll
    for (int j = 0; j < 4; j++) o[j] = o[j] * (1.0f / 6.0f) + b3[c + j];
    *(f32x4*)(out + (size_t)n * CH + c) = o;
  }
}

extern "C" void kernel_launch(void* const* d_in, const int* in_sizes, int n_in,
                              void* d_out, int out_size, void* d_ws, size_t ws_size,
                              hipStream_t stream) {
  const float* x  = (const float*)d_in[0];
  const int*   ei = (const int*)d_in[1];
  const float* W_[4]  = {(const float*)d_in[2], (const float*)d_in[6],
                         (const float*)d_in[10], (const float*)d_in[14]};
  const float* AS_[4] = {(const float*)d_in[3], (const float*)d_in[7],
                         (const float*)d_in[11], (const float*)d_in[15]};
  const float* AD_[4] = {(const float*)d_in[4], (const float*)d_in[8],
                         (const float*)d_in[12], (const float*)d_in[16]};
  const float* B_[4]  = {(const float*)d_in[5], (const float*)d_in[9],
                         (const float*)d_in[13], (const float*)d_in[17]};
  float* out = (float*)d_out;

  // ---- workspace layout ----
  char* w = (char*)d_ws;
  _Float16* feat = (_Float16*)w;                  // [N,384] fp16 GEMM out
  w += (size_t)N_NODES * F_HID * 2;
  unsigned short* Apk = (unsigned short*)w;       // packed split-bf16 A (also layer-0 x)
  w += (size_t)M_PAD * 2 * F_HID * 2;
  unsigned short* Wt0 = (unsigned short*)w; w += (size_t)F_HID * 2 * K0PAD * 2;
  unsigned short* Wt1 = (unsigned short*)w; w += (size_t)F_HID * 2 * F_HID * 2;
  unsigned short* Wt2 = (unsigned short*)w; w += (size_t)F_HID * 2 * F_HID * 2;
  unsigned short* Wt3 = (unsigned short*)w; w += (size_t)F_HID * 2 * F_HID * 2;
  float* als0 = (float*)w; w += (size_t)N_NODES * HEADS * 4;
  float* ald0 = (float*)w; w += (size_t)N_NODES * HEADS * 4;
  float* als1 = (float*)w; w += (size_t)N_NODES * HEADS * 4;
  float* ald1 = (float*)w; w += (size_t)N_NODES * HEADS * 4;
  float* va  = (float*)w; w += (size_t)4 * F_HID * 12 * 4;
  int* off = (int*)w; w += (N_NODES + 1) * 4;
  int* cur = (int*)w; w += N_NODES * 4;
  int* deg = (int*)w; w += N_NODES * 4;
  int* csr = (int*)w;

  // ---- CSR build ----
  (void)hipMemsetAsync(deg, 0, N_NODES * sizeof(int), stream);
  count_kernel<<<cdiv(N_EDGES, 256), 256, 0, stream>>>(ei, deg);
  scan_kernel<<<1, 256, 0, stream>>>(deg, off);
  (void)hipMemcpyAsync(cur, off, N_NODES * sizeof(int), hipMemcpyDeviceToDevice, stream);
  scatter_kernel<<<cdiv(N_EDGES, 256), 256, 0, stream>>>(ei, cur, csr);

  // ---- pack inputs + va + layer-0 al ----
  convert_x<<<cdiv(M_PAD * (K0PAD / 8), 256), 256, 0, stream>>>(x, Apk);
  convert_W<<<cdiv(F_HID * (K0PAD / 8), 256), 256, 0, stream>>>(W_[0], Wt0, IN_DIM, K0PAD);
  convert_W<<<cdiv(F_HID * (F_HID / 8), 256), 256, 0, stream>>>(W_[1], Wt1, F_HID, F_HID);
  convert_W<<<cdiv(F_HID * (F_HID / 8), 256), 256, 0, stream>>>(W_[2], Wt2, F_HID, F_HID);
  convert_W<<<cdiv(F_HID * (F_HID / 8), 256), 256, 0, stream>>>(W_[3], Wt3, F_HID, F_HID);
  (void)hipMemsetAsync((char*)Apk + (size_t)N_NODES * 4 * F_HID, 0,
                       (size_t)(M_PAD - N_NODES) * 4 * F_HID, stream);
  va_kernel<<<cdiv(4 * F_HID * 12, 256), 256, 0, stream>>>(
      W_[0], W_[1], W_[2], W_[3], AS_[0], AD_[0], AS_[1], AD_[1],
      AS_[2], AD_[2], AS_[3], AD_[3], va);
  al0_kernel<<<N_NODES / 4, 256, 0, stream>>>(x, va, als0, ald0);

  const int gemm_grid = 8 * cdiv(NBM, 8) * 3;  // 1176, XCD-grouped
  const int agg_grid = N_NODES / 4;            // 12500

  // ---- Layer 0 (K=160 packed): reads al buf0, writes al buf1 ----
  gemm_mfma<K0PAD><<<gemm_grid, 256, 0, stream>>>(Apk, Wt0, feat);
  agg_hidden<<<agg_grid, 384, 0, stream>>>(feat, off, csr, als0, ald0, B_[0],
                                           va + 1 * F_HID * 12, als1, ald1, Apk);

  // ---- Layer 1: reads buf1, writes buf0 ----
  gemm_mfma<F_HID><<<gemm_grid, 256, 0, stream>>>(Apk, Wt1, feat);
  agg_hidden<<<agg_grid, 384, 0, stream>>>(feat, off, csr, als1, ald1, B_[1],
                                           va + 2 * F_HID * 12, als0, ald0, Apk);

  // ---- Layer 2: reads buf0, writes buf1 ----
  gemm_mfma<F_HID><<<gemm_grid, 256, 0, stream>>>(Apk, Wt2, feat);
  agg_hidden<<<agg_grid, 384, 0, stream>>>(feat, off, csr, als0, ald0, B_[2],
                                           va + 3 * F_HID * 12, als1, ald1, Apk);

  // ---- Layer 3 (mean over heads): reads buf1 ----
  gemm_mfma<F_HID><<<gemm_grid, 256, 0, stream>>>(Apk, Wt3, feat);
  agg_out<<<agg_grid, 384, 0, stream>>>(feat, off, csr, als1, ald1, B_[3], out);
}

// Round 7
// 857.987 us; speedup vs baseline: 1.3779x; 1.3779x over previous
//
#include <hip/hip_runtime.h>

#define N_NODES 50000
#define M_PAD 50048      // N_NODES rounded up to 128
#define N_EDGES 500000
#define HEADS 6
#define CH 64
#define F_HID 384
#define IN_DIM 131
#define K0PAD 160        // layer-0 K padded to multiple of 32
#define CAP 64           // edge chunk per node
#define NBM 391          // cdiv(N_NODES,128)

static inline int cdiv(int a, int b) { return (a + b - 1) / b; }

typedef __attribute__((ext_vector_type(8))) __bf16 bf16x8;
typedef __attribute__((ext_vector_type(4))) float f32x4;
typedef __attribute__((ext_vector_type(8))) unsigned short us8;
typedef __attribute__((ext_vector_type(4))) unsigned short us4;
typedef __attribute__((ext_vector_type(4))) _Float16 f16x4;

// round-to-nearest-even fp32 -> bf16 split: v ~= hi + lo
__device__ __forceinline__ void bsplit(float v, unsigned short& h, unsigned short& l) {
  unsigned u = __builtin_bit_cast(unsigned, v);
  unsigned hr = (u + 0x7FFFu + ((u >> 16) & 1u)) >> 16;
  h = (unsigned short)hr;
  float hf = __builtin_bit_cast(float, hr << 16);
  float r = v - hf;
  unsigned u2 = __builtin_bit_cast(unsigned, r);
  unsigned lr = (u2 + 0x7FFFu + ((u2 >> 16) & 1u)) >> 16;
  l = (unsigned short)lr;
}

__device__ __forceinline__ void gload16(const void* g, void* lds) {
  __builtin_amdgcn_global_load_lds((const __attribute__((address_space(1))) void*)g,
                                   (__attribute__((address_space(3))) void*)lds, 16, 0, 0);
}

// ---------------- CSR build ----------------
__global__ void count_kernel(const int* __restrict__ ei, int* __restrict__ deg) {
  int e = blockIdx.x * blockDim.x + threadIdx.x;
  if (e < N_EDGES) atomicAdd(&deg[ei[N_EDGES + e]], 1);
}

__global__ void scan_kernel(const int* __restrict__ deg, int* __restrict__ off) {
  __shared__ int sdata[256];
  int tid = threadIdx.x;
  int carry = 0;
  if (tid == 0) off[0] = 0;
  for (int base = 0; base < N_NODES; base += 1024) {
    int idx0 = base + tid * 4;
    int v[4]; int s = 0;
#pragma unroll
    for (int j = 0; j < 4; j++) {
      v[j] = (idx0 + j < N_NODES) ? deg[idx0 + j] : 0;
      s += v[j];
    }
    sdata[tid] = s;
    __syncthreads();
    for (int o = 1; o < 256; o <<= 1) {
      int x = (tid >= o) ? sdata[tid - o] : 0;
      __syncthreads();
      sdata[tid] += x;
      __syncthreads();
    }
    int excl = sdata[tid] - s + carry;
    int total = sdata[255];
    int run = excl;
#pragma unroll
    for (int j = 0; j < 4; j++) {
      run += v[j];
      if (idx0 + j < N_NODES) off[idx0 + j + 1] = run;
    }
    carry += total;
    __syncthreads();
  }
}

__global__ void scatter_kernel(const int* __restrict__ ei, int* __restrict__ cursor,
                               int* __restrict__ csr_src) {
  int e = blockIdx.x * blockDim.x + threadIdx.x;
  if (e < N_EDGES) {
    int d = ei[N_EDGES + e];
    int p = atomicAdd(&cursor[d], 1);
    csr_src[p] = ei[e];
  }
}

// ---------------- packers ----------------
__global__ void convert_x(const float* __restrict__ x, unsigned short* __restrict__ xp) {
  int t = blockIdx.x * blockDim.x + threadIdx.x;
  const int npc = K0PAD / 8;
  if (t >= M_PAD * npc) return;
  int r = t / npc, g = t % npc;
  int kt = g >> 2, kb = g & 3;
  int k0 = kt * 32 + kb * 8;
  us8 hv, lv;
#pragma unroll
  for (int j = 0; j < 8; j++) {
    int k = k0 + j;
    float v = (r < N_NODES && k < IN_DIM) ? x[(long)r * IN_DIM + k] : 0.0f;
    unsigned short h, l; bsplit(v, h, l);
    hv[j] = h; lv[j] = l;
  }
  char* base = (char*)xp + (size_t)r * (4 * K0PAD) + kt * 128;
  int x7 = r & 7;
  *(us8*)(base + (((2 * kb) ^ x7) << 4)) = hv;
  *(us8*)(base + (((2 * kb + 1) ^ x7) << 4)) = lv;
}

__global__ void convert_W(const float* __restrict__ W, unsigned short* __restrict__ Wt,
                          int Kreal, int Kpad) {
  int t = blockIdx.x * blockDim.x + threadIdx.x;
  int npc = Kpad >> 3;
  if (t >= F_HID * npc) return;
  int n = t / npc, g = t % npc;
  int kt = g >> 2, kb = g & 3;
  int k0 = kt * 32 + kb * 8;
  us8 hv, lv;
#pragma unroll
  for (int j = 0; j < 8; j++) {
    int k = k0 + j;
    float v = (k < Kreal) ? W[(long)k * F_HID + n] : 0.0f;
    unsigned short h, l; bsplit(v, h, l);
    hv[j] = h; lv[j] = l;
  }
  char* base = (char*)Wt + (size_t)n * (4 * Kpad) + kt * 128;
  int x7 = n & 7;
  *(us8*)(base + (((2 * kb) ^ x7) << 4)) = hv;
  *(us8*)(base + (((2 * kb + 1) ^ x7) << 4)) = lv;
}

// ---------------- va precompute (layer 0 only): va0[k][j] = sum_c W0[k,h*64+c]*a[h][c]
__global__ void va_kernel(const float* __restrict__ W0,
                          const float* __restrict__ as0, const float* __restrict__ ad0,
                          float* __restrict__ va) {
  int t = blockIdx.x * blockDim.x + threadIdx.x;
  if (t >= F_HID * 12) return;
  int k = t / 12, j = t % 12;
  int h = j % 6;
  const float* al = (j < 6) ? as0 : ad0;
  float acc = 0.0f;
  if (k < IN_DIM) {
    const float* wrow = W0 + (size_t)k * F_HID + h * CH;
    const float* arow = al + h * CH;
#pragma unroll 8
    for (int c = 0; c < CH; ++c) acc += wrow[c] * arow[c];
  }
  va[t] = acc;
}

// ---------------- layer-0 attention logits straight from x ----------------
__global__ __launch_bounds__(256) void al0_kernel(const float* __restrict__ x,
                                                  const float* __restrict__ va,
                                                  float* __restrict__ als,
                                                  float* __restrict__ ald) {
  __shared__ float va0L[IN_DIM * 12];
  int tid = threadIdx.x;
  for (int i = tid; i < IN_DIM * 12; i += 256) va0L[i] = va[i];
  __syncthreads();
  int sub = tid >> 6, lane = tid & 63;
  int n = blockIdx.x * 4 + sub;
  float acc[12];
#pragma unroll
  for (int j = 0; j < 12; ++j) acc[j] = 0.0f;
  for (int k = lane; k < IN_DIM; k += 64) {
    float xv = x[(size_t)n * IN_DIM + k];
#pragma unroll
    for (int j = 0; j < 12; ++j) acc[j] += xv * va0L[k * 12 + j];
  }
#pragma unroll
  for (int o = 32; o; o >>= 1)
#pragma unroll
    for (int j = 0; j < 12; ++j) acc[j] += __shfl_xor(acc[j], o);
  if (lane < 6) als[n * 6 + lane] = acc[lane];
  else if (lane < 12) ald[n * 6 + lane - 6] = acc[lane];
}

// ---------------- split-bf16 MFMA GEMM, fp16 output, XCD-grouped swizzle ----------
template <int K>
__global__ __launch_bounds__(256) void gemm_mfma(const unsigned short* __restrict__ Ap,
                                                 const unsigned short* __restrict__ Bp,
                                                 _Float16* __restrict__ O) {
  constexpr int NKT = K / 32;
  constexpr size_t RB = 4 * K;
  __shared__ __align__(16) char smA[16384];
  __shared__ __align__(16) char smB[16384];
  int xcd = blockIdx.x & 7, slot = blockIdx.x >> 3;
  int bn = slot % 3, tt = slot / 3;
  int bm = tt * 8 + xcd;
  if (bm >= NBM) return;
  int row0 = bm * 128, col0 = bn * 128;
  int tid = threadIdx.x, lane = tid & 63, wv = tid >> 6;
  int wy = wv >> 1, wx = wv & 1;

  f32x4 acc[4][4];
#pragma unroll
  for (int i = 0; i < 4; i++)
#pragma unroll
    for (int j = 0; j < 4; j++) acc[i][j] = (f32x4)0.0f;

  const char* Ab = (const char*)Ap + (size_t)row0 * RB;
  const char* Bb = (const char*)Bp + (size_t)col0 * RB;

  int kb2 = (lane >> 4) * 2;
  int x7 = lane & 7;
  int rA = wy * 64 + (lane & 15);
  int rB = wx * 64 + (lane & 15);

  for (int kt = 0; kt < NKT; ++kt) {
#pragma unroll
    for (int i = 0; i < 4; ++i) {
      int b = wv * 4096 + i * 1024;
      int bl = b + lane * 16;
      int r = bl >> 7, q = bl & 127;
      gload16(Ab + (size_t)r * RB + kt * 128 + q, smA + b);
      gload16(Bb + (size_t)r * RB + kt * 128 + q, smB + b);
    }
    __syncthreads();

    bf16x8 ah[4], alo[4], bh[4], blo[4];
#pragma unroll
    for (int mf = 0; mf < 4; ++mf) {
      const char* p = smA + (rA + mf * 16) * 128;
      ah[mf]  = *(const bf16x8*)(p + ((kb2 ^ x7) << 4));
      alo[mf] = *(const bf16x8*)(p + (((kb2 + 1) ^ x7) << 4));
    }
#pragma unroll
    for (int nf = 0; nf < 4; ++nf) {
      const char* p = smB + (rB + nf * 16) * 128;
      bh[nf]  = *(const bf16x8*)(p + ((kb2 ^ x7) << 4));
      blo[nf] = *(const bf16x8*)(p + (((kb2 + 1) ^ x7) << 4));
    }
#pragma unroll
    for (int mf = 0; mf < 4; ++mf)
#pragma unroll
      for (int nf = 0; nf < 4; ++nf) {
        acc[mf][nf] = __builtin_amdgcn_mfma_f32_16x16x32_bf16(ah[mf], bh[nf], acc[mf][nf], 0, 0, 0);
        acc[mf][nf] = __builtin_amdgcn_mfma_f32_16x16x32_bf16(alo[mf], bh[nf], acc[mf][nf], 0, 0, 0);
        acc[mf][nf] = __builtin_amdgcn_mfma_f32_16x16x32_bf16(ah[mf], blo[nf], acc[mf][nf], 0, 0, 0);
      }
    __syncthreads();
  }

  int cr = (lane >> 4) * 4, cc = lane & 15;
#pragma unroll
  for (int mf = 0; mf < 4; ++mf)
#pragma unroll
    for (int r = 0; r < 4; ++r) {
      int row = row0 + wy * 64 + mf * 16 + cr + r;
      if (row < N_NODES) {
#pragma unroll
        for (int nf = 0; nf < 4; ++nf)
          O[(size_t)row * F_HID + col0 + wx * 64 + nf * 16 + cc] = (_Float16)acc[mf][nf][r];
      }
    }
}

// ---------------- attention dots (fp16 feat), layers 1-3 ----------------
__global__ void dots_kernel(const _Float16* __restrict__ feat,
                            const float* __restrict__ a_src,
                            const float* __restrict__ a_dst,
                            float* __restrict__ al_s, float* __restrict__ al_d) {
  int n = (blockIdx.x * blockDim.x + threadIdx.x) >> 6;
  int lane = threadIdx.x & 63;
  if (n >= N_NODES) return;
#pragma unroll
  for (int h = 0; h < HEADS; h++) {
    float v = (float)feat[(long)n * F_HID + h * CH + lane];
    float p = v * a_src[h * CH + lane];
    float q = v * a_dst[h * CH + lane];
#pragma unroll
    for (int o = 32; o; o >>= 1) {
      p += __shfl_xor(p, o);
      q += __shfl_xor(q, o);
    }
    if (lane == 0) {
      al_s[n * HEADS + h] = p;
      al_d[n * HEADS + h] = q;
    }
  }
}

// ---------------- phase-split agg core ----------------
// Block: 384 threads = 4 nodes x 96 threads. Per 64-edge chunk:
//   A) parallel logit computation into LDS (deg x 6 items over 96 threads)
//   B) PARALLEL softmax scan: 24 (node,head) pairs x 16 lanes; strided max/exp/sum
//      + 4-step __shfl_xor butterfly (stays in 16-lane group); (m,s) state replicated
//   C) gather loop: pure FMA over independent global loads, LDS-broadcast weights
#define AGG_CORE(FEAT, OFF, CSR, ALS, ALD)                                        \
  int tid = threadIdx.x;                                                          \
  int sub = tid / 96, t96 = tid - sub * 96;                                       \
  int nb = blockIdx.x * 4;                                                        \
  int n = nb + sub;                                                               \
  int c4 = t96 * 4, h = t96 >> 4;                                                 \
  int o_[5];                                                                      \
  _Pragma("unroll")                                                               \
  for (int k = 0; k < 5; ++k) o_[k] = OFF[nb + k];                                \
  int dmax = 0;                                                                   \
  _Pragma("unroll")                                                               \
  for (int k = 0; k < 4; ++k) dmax = max(dmax, o_[k + 1] - o_[k]);                \
  int nch = (dmax + CAP - 1) / CAP; if (nch < 1) nch = 1;                         \
  int s0 = o_[sub], deg = o_[sub + 1] - o_[sub];                                  \
  int pr = tid >> 4, pl = tid & 15;                                               \
  int psub = pr / 6, ph = pr - psub * 6;                                          \
  int pdeg = o_[psub + 1] - o_[psub];                                             \
  float m_run = -INFINITY, s_run = 0.0f;                                          \
  float a0 = 0, a1 = 0, a2 = 0, a3 = 0;                                           \
  for (int ch = 0; ch < nch; ++ch) {                                              \
    int base = ch * CAP;                                                          \
    int cl = deg - base; cl = cl < 0 ? 0 : (cl > CAP ? CAP : cl);                 \
    if (t96 < cl) lsrc[sub][t96] = CSR[s0 + base + t96];                          \
    for (int j = t96; j < cl * 6; j += 96) {                                      \
      int i = j / 6, hh = j - i * 6;                                              \
      int s = CSR[s0 + base + i];                                                 \
      float e = ALS[s * 6 + hh] + ALD[n * 6 + hh];                                \
      e = e > 0.0f ? e : 0.2f * e;                                                \
      lew[sub][hh][i] = e;                                                        \
    }                                                                             \
    __syncthreads();                                                              \
    int pcl = pdeg - base; pcl = pcl < 0 ? 0 : (pcl > CAP ? CAP : pcl);           \
    float asc = 1.0f;                                                             \
    if (pcl > 0) {                                                                \
      float mc = -INFINITY;                                                       \
      for (int i = pl; i < pcl; i += 16) mc = fmaxf(mc, lew[psub][ph][i]);        \
      mc = fmaxf(mc, __shfl_xor(mc, 1));                                          \
      mc = fmaxf(mc, __shfl_xor(mc, 2));                                          \
      mc = fmaxf(mc, __shfl_xor(mc, 4));                                          \
      mc = fmaxf(mc, __shfl_xor(mc, 8));                                          \
      float mn = fmaxf(m_run, mc);                                                \
      asc = (m_run == -INFINITY) ? 0.0f : __expf(m_run - mn);                     \
      float scp = 0.0f;                                                           \
      for (int i = pl; i < pcl; i += 16) {                                        \
        float wv = __expf(lew[psub][ph][i] - mn);                                 \
        lew[psub][ph][i] = wv;                                                    \
        scp += wv;                                                                \
      }                                                                           \
      scp += __shfl_xor(scp, 1);                                                  \
      scp += __shfl_xor(scp, 2);                                                  \
      scp += __shfl_xor(scp, 4);                                                  \
      scp += __shfl_xor(scp, 8);                                                  \
      s_run = s_run * asc + scp;                                                  \
      m_run = mn;                                                                 \
    }                                                                             \
    if (pl == 0) {                                                                \
      lasc[psub][ph] = asc;                                                       \
      if (ch == nch - 1) lrr[psub][ph] = 1.0f / (s_run + 1e-16f);                 \
    }                                                                             \
    __syncthreads();                                                              \
    float cc0 = 0, cc1 = 0, cc2 = 0, cc3 = 0;                                     \
    for (int i = 0; i < cl; ++i) {                                                \
      int s = lsrc[sub][i];                                                       \
      float wv = lew[sub][h][i];                                                  \
      f16x4 fv = *(const f16x4*)(FEAT + (size_t)s * F_HID + c4);                  \
      cc0 += wv * (float)fv[0];                                                   \
      cc1 += wv * (float)fv[1];                                                   \
      cc2 += wv * (float)fv[2];                                                   \
      cc3 += wv * (float)fv[3];                                                   \
    }                                                                             \
    float asc2 = lasc[sub][h];                                                    \
    a0 = a0 * asc2 + cc0; a1 = a1 * asc2 + cc1;                                   \
    a2 = a2 * asc2 + cc2; a3 = a3 * asc2 + cc3;                                   \
    __syncthreads();                                                              \
  }                                                                               \
  float rr = lrr[sub][h];

// hidden layers: normalize + bias + ELU + split-bf16 pack
__global__ __launch_bounds__(384) void agg_hidden(const _Float16* __restrict__ feat,
                                                  const int* __restrict__ off,
                                                  const int* __restrict__ csr_src,
                                                  const float* __restrict__ al_s,
                                                  const float* __restrict__ al_d,
                                                  const float* __restrict__ bias,
                                                  unsigned short* __restrict__ Apk) {
  __shared__ int   lsrc[4][CAP + 1];
  __shared__ float lew[4][6][CAP + 1];
  __shared__ float lasc[4][6];
  __shared__ float lrr[4][6];
  AGG_CORE(feat, off, csr_src, al_s, al_d)
  float v0 = a0 * rr + bias[c4 + 0];
  float v1 = a1 * rr + bias[c4 + 1];
  float v2 = a2 * rr + bias[c4 + 2];
  float v3 = a3 * rr + bias[c4 + 3];
  v0 = v0 > 0.0f ? v0 : (__expf(v0) - 1.0f);
  v1 = v1 > 0.0f ? v1 : (__expf(v1) - 1.0f);
  v2 = v2 > 0.0f ? v2 : (__expf(v2) - 1.0f);
  v3 = v3 > 0.0f ? v3 : (__expf(v3) - 1.0f);
  unsigned short h0, l0, h1, l1, h2, l2, h3, l3;
  bsplit(v0, h0, l0);
  bsplit(v1, h1, l1);
  bsplit(v2, h2, l2);
  bsplit(v3, h3, l3);
  us4 hv, lv;
  hv[0] = h0; hv[1] = h1; hv[2] = h2; hv[3] = h3;
  lv[0] = l0; lv[1] = l1; lv[2] = l2; lv[3] = l3;
  int kt = c4 >> 5, kb = (c4 >> 3) & 3, jb = (c4 & 7) * 2;
  char* basep = (char*)Apk + (size_t)n * (4 * F_HID) + kt * 128;
  int x7 = n & 7;
  *(us4*)(basep + (((2 * kb) ^ x7) << 4) + jb) = hv;
  *(us4*)(basep + (((2 * kb + 1) ^ x7) << 4) + jb) = lv;
}

// output layer: normalize + head-mean + bias
__global__ __launch_bounds__(384) void agg_out(const _Float16* __restrict__ feat,
                                               const int* __restrict__ off,
                                               const int* __restrict__ csr_src,
                                               const float* __restrict__ al_s,
                                               const float* __restrict__ al_d,
                                               const float* __restrict__ b3,
                                               float* __restrict__ out) {
  __shared__ int   lsrc[4][CAP + 1];
  __shared__ float lew[4][6][CAP + 1];
  __shared__ float lasc[4][6];
  __shared__ float lrr[4][6];
  __shared__ float red[4][384];
  AGG_CORE(feat, off, csr_src, al_s, al_d)
  red[sub][c4 + 0] = a0 * rr;
  red[sub][c4 + 1] = a1 * rr;
  red[sub][c4 + 2] = a2 * rr;
  red[sub][c4 + 3] = a3 * rr;
  __syncthreads();
  if (t96 < 16) {
    int c = t96 * 4;
    f32x4 o = (f32x4)0.0f;
#pragma unroll
    for (int hh = 0; hh < HEADS; hh++) {
#pragma unroll
      for (int j = 0; j < 4; j++) o[j] += red[sub][hh * CH + c + j];
    }
#pragma unroll
    for (int j = 0; j < 4; j++) o[j] = o[j] * (1.0f / 6.0f) + b3[c + j];
    *(f32x4*)(out + (size_t)n * CH + c) = o;
  }
}

extern "C" void kernel_launch(void* const* d_in, const int* in_sizes, int n_in,
                              void* d_out, int out_size, void* d_ws, size_t ws_size,
                              hipStream_t stream) {
  const float* x  = (const float*)d_in[0];
  const int*   ei = (const int*)d_in[1];
  const float* W_[4]  = {(const float*)d_in[2], (const float*)d_in[6],
                         (const float*)d_in[10], (const float*)d_in[14]};
  const float* AS_[4] = {(const float*)d_in[3], (const float*)d_in[7],
                         (const float*)d_in[11], (const float*)d_in[15]};
  const float* AD_[4] = {(const float*)d_in[4], (const float*)d_in[8],
                         (const float*)d_in[12], (const float*)d_in[16]};
  const float* B_[4]  = {(const float*)d_in[5], (const float*)d_in[9],
                         (const float*)d_in[13], (const float*)d_in[17]};
  float* out = (float*)d_out;

  // ---- workspace layout ----
  char* w = (char*)d_ws;
  _Float16* feat = (_Float16*)w;                  // [N,384] fp16 GEMM out
  w += (size_t)N_NODES * F_HID * 2;
  unsigned short* Apk = (unsigned short*)w;       // packed split-bf16 A (also layer-0 x)
  w += (size_t)M_PAD * 2 * F_HID * 2;
  unsigned short* Wt0 = (unsigned short*)w; w += (size_t)F_HID * 2 * K0PAD * 2;
  unsigned short* Wt1 = (unsigned short*)w; w += (size_t)F_HID * 2 * F_HID * 2;
  unsigned short* Wt2 = (unsigned short*)w; w += (size_t)F_HID * 2 * F_HID * 2;
  unsigned short* Wt3 = (unsigned short*)w; w += (size_t)F_HID * 2 * F_HID * 2;
  float* als = (float*)w; w += (size_t)N_NODES * HEADS * 4;
  float* ald = (float*)w; w += (size_t)N_NODES * HEADS * 4;
  float* va  = (float*)w; w += (size_t)F_HID * 12 * 4;
  int* off = (int*)w; w += (N_NODES + 1) * 4;
  int* cur = (int*)w; w += N_NODES * 4;
  int* deg = (int*)w; w += N_NODES * 4;
  int* csr = (int*)w;

  // ---- CSR build ----
  (void)hipMemsetAsync(deg, 0, N_NODES * sizeof(int), stream);
  count_kernel<<<cdiv(N_EDGES, 256), 256, 0, stream>>>(ei, deg);
  scan_kernel<<<1, 256, 0, stream>>>(deg, off);
  (void)hipMemcpyAsync(cur, off, N_NODES * sizeof(int), hipMemcpyDeviceToDevice, stream);
  scatter_kernel<<<cdiv(N_EDGES, 256), 256, 0, stream>>>(ei, cur, csr);

  // ---- pack inputs + layer-0 al ----
  convert_x<<<cdiv(M_PAD * (K0PAD / 8), 256), 256, 0, stream>>>(x, Apk);
  convert_W<<<cdiv(F_HID * (K0PAD / 8), 256), 256, 0, stream>>>(W_[0], Wt0, IN_DIM, K0PAD);
  convert_W<<<cdiv(F_HID * (F_HID / 8), 256), 256, 0, stream>>>(W_[1], Wt1, F_HID, F_HID);
  convert_W<<<cdiv(F_HID * (F_HID / 8), 256), 256, 0, stream>>>(W_[2], Wt2, F_HID, F_HID);
  convert_W<<<cdiv(F_HID * (F_HID / 8), 256), 256, 0, stream>>>(W_[3], Wt3, F_HID, F_HID);
  (void)hipMemsetAsync((char*)Apk + (size_t)N_NODES * 4 * F_HID, 0,
                       (size_t)(M_PAD - N_NODES) * 4 * F_HID, stream);
  va_kernel<<<cdiv(F_HID * 12, 256), 256, 0, stream>>>(W_[0], AS_[0], AD_[0], va);
  al0_kernel<<<N_NODES / 4, 256, 0, stream>>>(x, va, als, ald);

  const int gemm_grid = 8 * cdiv(NBM, 8) * 3;  // XCD-grouped
  const int dots_grid = cdiv(N_NODES, 4);
  const int agg_grid = N_NODES / 4;            // 12500

  // ---- Layer 0 (K=160 packed) ----
  gemm_mfma<K0PAD><<<gemm_grid, 256, 0, stream>>>(Apk, Wt0, feat);
  agg_hidden<<<agg_grid, 384, 0, stream>>>(feat, off, csr, als, ald, B_[0], Apk);

  // ---- Layers 1,2 (K=384) ----
  gemm_mfma<F_HID><<<gemm_grid, 256, 0, stream>>>(Apk, Wt1, feat);
  dots_kernel<<<dots_grid, 256, 0, stream>>>(feat, AS_[1], AD_[1], als, ald);
  agg_hidden<<<agg_grid, 384, 0, stream>>>(feat, off, csr, als, ald, B_[1], Apk);

  gemm_mfma<F_HID><<<gemm_grid, 256, 0, stream>>>(Apk, Wt2, feat);
  dots_kernel<<<dots_grid, 256, 0, stream>>>(feat, AS_[2], AD_[2], als, ald);
  agg_hidden<<<agg_grid, 384, 0, stream>>>(feat, off, csr, als, ald, B_[2], Apk);

  // ---- Layer 3 (K=384, mean over heads) ----
  gemm_mfma<F_HID><<<gemm_grid, 256, 0, stream>>>(Apk, Wt3, feat);
  dots_kernel<<<dots_grid, 256, 0, stream>>>(feat, AS_[3], AD_[3], als, ald);
  agg_out<<<agg_grid, 384, 0, stream>>>(feat, off, csr, als, ald, B_[3], out);
}

// Round 8
// 716.080 us; speedup vs baseline: 1.6510x; 1.1982x over previous
//
#include <hip/hip_runtime.h>

#define N_NODES 50000
#define M_PAD 50048      // N_NODES rounded up to 128
#define N_EDGES 500000
#define HEADS 6
#define CH 64
#define F_HID 384
#define IN_DIM 131
#define K0PAD 160        // layer-0 K padded to multiple of 32
#define CAP 64           // edge chunk per node
#define NBM 391          // cdiv(N_NODES,128)

static inline int cdiv(int a, int b) { return (a + b - 1) / b; }

typedef __attribute__((ext_vector_type(8))) __bf16 bf16x8;
typedef __attribute__((ext_vector_type(4))) float f32x4;
typedef __attribute__((ext_vector_type(8))) unsigned short us8;
typedef __attribute__((ext_vector_type(4))) unsigned short us4;
typedef __attribute__((ext_vector_type(4))) _Float16 f16x4;

// round-to-nearest-even fp32 -> bf16 split: v ~= hi + lo
__device__ __forceinline__ void bsplit(float v, unsigned short& h, unsigned short& l) {
  unsigned u = __builtin_bit_cast(unsigned, v);
  unsigned hr = (u + 0x7FFFu + ((u >> 16) & 1u)) >> 16;
  h = (unsigned short)hr;
  float hf = __builtin_bit_cast(float, hr << 16);
  float r = v - hf;
  unsigned u2 = __builtin_bit_cast(unsigned, r);
  unsigned lr = (u2 + 0x7FFFu + ((u2 >> 16) & 1u)) >> 16;
  l = (unsigned short)lr;
}

__device__ __forceinline__ void gload16(const void* g, void* lds) {
  __builtin_amdgcn_global_load_lds((const __attribute__((address_space(1))) void*)g,
                                   (__attribute__((address_space(3))) void*)lds, 16, 0, 0);
}

// ---------------- CSR build ----------------
__global__ void count_kernel(const int* __restrict__ ei, int* __restrict__ deg) {
  int e = blockIdx.x * blockDim.x + threadIdx.x;
  if (e < N_EDGES) atomicAdd(&deg[ei[N_EDGES + e]], 1);
}

__global__ void scan_kernel(const int* __restrict__ deg, int* __restrict__ off) {
  __shared__ int sdata[256];
  int tid = threadIdx.x;
  int carry = 0;
  if (tid == 0) off[0] = 0;
  for (int base = 0; base < N_NODES; base += 1024) {
    int idx0 = base + tid * 4;
    int v[4]; int s = 0;
#pragma unroll
    for (int j = 0; j < 4; j++) {
      v[j] = (idx0 + j < N_NODES) ? deg[idx0 + j] : 0;
      s += v[j];
    }
    sdata[tid] = s;
    __syncthreads();
    for (int o = 1; o < 256; o <<= 1) {
      int x = (tid >= o) ? sdata[tid - o] : 0;
      __syncthreads();
      sdata[tid] += x;
      __syncthreads();
    }
    int excl = sdata[tid] - s + carry;
    int total = sdata[255];
    int run = excl;
#pragma unroll
    for (int j = 0; j < 4; j++) {
      run += v[j];
      if (idx0 + j < N_NODES) off[idx0 + j + 1] = run;
    }
    carry += total;
    __syncthreads();
  }
}

__global__ void scatter_kernel(const int* __restrict__ ei, int* __restrict__ cursor,
                               int* __restrict__ csr_src) {
  int e = blockIdx.x * blockDim.x + threadIdx.x;
  if (e < N_EDGES) {
    int d = ei[N_EDGES + e];
    int p = atomicAdd(&cursor[d], 1);
    csr_src[p] = ei[e];
  }
}

// ---------------- packers ----------------
__global__ void convert_x(const float* __restrict__ x, unsigned short* __restrict__ xp) {
  int t = blockIdx.x * blockDim.x + threadIdx.x;
  const int npc = K0PAD / 8;
  if (t >= M_PAD * npc) return;
  int r = t / npc, g = t % npc;
  int kt = g >> 2, kb = g & 3;
  int k0 = kt * 32 + kb * 8;
  us8 hv, lv;
#pragma unroll
  for (int j = 0; j < 8; j++) {
    int k = k0 + j;
    float v = (r < N_NODES && k < IN_DIM) ? x[(long)r * IN_DIM + k] : 0.0f;
    unsigned short h, l; bsplit(v, h, l);
    hv[j] = h; lv[j] = l;
  }
  char* base = (char*)xp + (size_t)r * (4 * K0PAD) + kt * 128;
  int x7 = r & 7;
  *(us8*)(base + (((2 * kb) ^ x7) << 4)) = hv;
  *(us8*)(base + (((2 * kb + 1) ^ x7) << 4)) = lv;
}

__global__ void convert_W0(const float* __restrict__ W, unsigned short* __restrict__ Wt) {
  int t = blockIdx.x * blockDim.x + threadIdx.x;
  const int npc = K0PAD >> 3;
  if (t >= F_HID * npc) return;
  int n = t / npc, g = t % npc;
  int kt = g >> 2, kb = g & 3;
  int k0 = kt * 32 + kb * 8;
  us8 hv, lv;
#pragma unroll
  for (int j = 0; j < 8; j++) {
    int k = k0 + j;
    float v = (k < IN_DIM) ? W[(long)k * F_HID + n] : 0.0f;
    unsigned short h, l; bsplit(v, h, l);
    hv[j] = h; lv[j] = l;
  }
  char* base = (char*)Wt + (size_t)n * (4 * K0PAD) + kt * 128;
  int x7 = n & 7;
  *(us8*)(base + (((2 * kb) ^ x7) << 4)) = hv;
  *(us8*)(base + (((2 * kb + 1) ^ x7) << 4)) = lv;
}

// layers 1-3 in one launch (gridDim.y = 3)
__global__ void convert_W123(const float* __restrict__ W1, const float* __restrict__ W2,
                             const float* __restrict__ W3, unsigned short* __restrict__ Wt1,
                             unsigned short* __restrict__ Wt2, unsigned short* __restrict__ Wt3) {
  int t = blockIdx.x * blockDim.x + threadIdx.x;
  const int npc = F_HID >> 3;
  if (t >= F_HID * npc) return;
  const float* W = blockIdx.y == 0 ? W1 : (blockIdx.y == 1 ? W2 : W3);
  unsigned short* Wt = blockIdx.y == 0 ? Wt1 : (blockIdx.y == 1 ? Wt2 : Wt3);
  int n = t / npc, g = t % npc;
  int kt = g >> 2, kb = g & 3;
  int k0 = kt * 32 + kb * 8;
  us8 hv, lv;
#pragma unroll
  for (int j = 0; j < 8; j++) {
    int k = k0 + j;
    float v = W[(long)k * F_HID + n];
    unsigned short h, l; bsplit(v, h, l);
    hv[j] = h; lv[j] = l;
  }
  char* base = (char*)Wt + (size_t)n * (4 * F_HID) + kt * 128;
  int x7 = n & 7;
  *(us8*)(base + (((2 * kb) ^ x7) << 4)) = hv;
  *(us8*)(base + (((2 * kb + 1) ^ x7) << 4)) = lv;
}

// ---------------- split-bf16 MFMA GEMM + fused attention dots ----------------
// Epilogue computes al_s/al_d for this block's rows x (2bn+wx) head from fp32 acc.
template <int K>
__global__ __launch_bounds__(256) void gemm_mfma(const unsigned short* __restrict__ Ap,
                                                 const unsigned short* __restrict__ Bp,
                                                 const float* __restrict__ AS,
                                                 const float* __restrict__ AD,
                                                 float* __restrict__ als,
                                                 float* __restrict__ ald,
                                                 _Float16* __restrict__ O) {
  constexpr int NKT = K / 32;
  constexpr size_t RB = 4 * K;
  __shared__ __align__(16) char smA[16384];
  __shared__ __align__(16) char smB[16384];
  int xcd = blockIdx.x & 7, slot = blockIdx.x >> 3;
  int bn = slot % 3, tt = slot / 3;
  int bm = tt * 8 + xcd;
  if (bm >= NBM) return;
  int row0 = bm * 128, col0 = bn * 128;
  int tid = threadIdx.x, lane = tid & 63, wv = tid >> 6;
  int wy = wv >> 1, wx = wv & 1;

  f32x4 acc[4][4];
#pragma unroll
  for (int i = 0; i < 4; i++)
#pragma unroll
    for (int j = 0; j < 4; j++) acc[i][j] = (f32x4)0.0f;

  const char* Ab = (const char*)Ap + (size_t)row0 * RB;
  const char* Bb = (const char*)Bp + (size_t)col0 * RB;

  int kb2 = (lane >> 4) * 2;
  int x7 = lane & 7;
  int rA = wy * 64 + (lane & 15);
  int rB = wx * 64 + (lane & 15);

  for (int kt = 0; kt < NKT; ++kt) {
#pragma unroll
    for (int i = 0; i < 4; ++i) {
      int b = wv * 4096 + i * 1024;
      int bl = b + lane * 16;
      int r = bl >> 7, q = bl & 127;
      gload16(Ab + (size_t)r * RB + kt * 128 + q, smA + b);
      gload16(Bb + (size_t)r * RB + kt * 128 + q, smB + b);
    }
    __syncthreads();

    bf16x8 ah[4], alo[4], bh[4], blo[4];
#pragma unroll
    for (int mf = 0; mf < 4; ++mf) {
      const char* p = smA + (rA + mf * 16) * 128;
      ah[mf]  = *(const bf16x8*)(p + ((kb2 ^ x7) << 4));
      alo[mf] = *(const bf16x8*)(p + (((kb2 + 1) ^ x7) << 4));
    }
#pragma unroll
    for (int nf = 0; nf < 4; ++nf) {
      const char* p = smB + (rB + nf * 16) * 128;
      bh[nf]  = *(const bf16x8*)(p + ((kb2 ^ x7) << 4));
      blo[nf] = *(const bf16x8*)(p + (((kb2 + 1) ^ x7) << 4));
    }
#pragma unroll
    for (int mf = 0; mf < 4; ++mf)
#pragma unroll
      for (int nf = 0; nf < 4; ++nf) {
        acc[mf][nf] = __builtin_amdgcn_mfma_f32_16x16x32_bf16(ah[mf], bh[nf], acc[mf][nf], 0, 0, 0);
        acc[mf][nf] = __builtin_amdgcn_mfma_f32_16x16x32_bf16(alo[mf], bh[nf], acc[mf][nf], 0, 0, 0);
        acc[mf][nf] = __builtin_amdgcn_mfma_f32_16x16x32_bf16(ah[mf], blo[nf], acc[mf][nf], 0, 0, 0);
      }
    __syncthreads();
  }

  int cr = (lane >> 4) * 4, cc = lane & 15;
  // ---- C write ----
#pragma unroll
  for (int mf = 0; mf < 4; ++mf)
#pragma unroll
    for (int r = 0; r < 4; ++r) {
      int row = row0 + wy * 64 + mf * 16 + cr + r;
      if (row < N_NODES) {
#pragma unroll
        for (int nf = 0; nf < 4; ++nf)
          O[(size_t)row * F_HID + col0 + wx * 64 + nf * 16 + cc] = (_Float16)acc[mf][nf][r];
      }
    }
  // ---- fused dots: head = 2*bn + wx; this wave holds its full 64 cols ----
  int head = bn * 2 + wx;
  float sa[4], da[4];
#pragma unroll
  for (int nf = 0; nf < 4; ++nf) {
    sa[nf] = AS[head * CH + nf * 16 + cc];
    da[nf] = AD[head * CH + nf * 16 + cc];
  }
#pragma unroll
  for (int mf = 0; mf < 4; ++mf)
#pragma unroll
    for (int r = 0; r < 4; ++r) {
      float ps = 0.0f, pd = 0.0f;
#pragma unroll
      for (int nf = 0; nf < 4; ++nf) {
        ps += acc[mf][nf][r] * sa[nf];
        pd += acc[mf][nf][r] * da[nf];
      }
#pragma unroll
      for (int o = 1; o < 16; o <<= 1) {
        ps += __shfl_xor(ps, o);
        pd += __shfl_xor(pd, o);
      }
      int row = row0 + wy * 64 + mf * 16 + cr + r;
      if (cc == 0 && row < N_NODES) {
        als[row * HEADS + head] = ps;
        ald[row * HEADS + head] = pd;
      }
    }
}

// ---------------- phase-split agg core (4 nodes x 96 thr; gather unrolled x4) ----
#define AGG_CORE(FEAT, OFF, CSR, ALS, ALD)                                        \
  int tid = threadIdx.x;                                                          \
  int sub = tid / 96, t96 = tid - sub * 96;                                       \
  int nb = blockIdx.x * 4;                                                        \
  int n = nb + sub;                                                               \
  int c4 = t96 * 4, h = t96 >> 4;                                                 \
  int o_[5];                                                                      \
  _Pragma("unroll")                                                               \
  for (int k = 0; k < 5; ++k) o_[k] = OFF[nb + k];                                \
  int dmax = 0;                                                                   \
  _Pragma("unroll")                                                               \
  for (int k = 0; k < 4; ++k) dmax = max(dmax, o_[k + 1] - o_[k]);                \
  int nch = (dmax + CAP - 1) / CAP; if (nch < 1) nch = 1;                         \
  int s0 = o_[sub], deg = o_[sub + 1] - o_[sub];                                  \
  int pr = tid >> 4, pl = tid & 15;                                               \
  int psub = pr / 6, ph = pr - psub * 6;                                          \
  int pdeg = o_[psub + 1] - o_[psub];                                             \
  float m_run = -INFINITY, s_run = 0.0f;                                          \
  float a0 = 0, a1 = 0, a2 = 0, a3 = 0;                                           \
  for (int ch = 0; ch < nch; ++ch) {                                              \
    int base = ch * CAP;                                                          \
    int cl = deg - base; cl = cl < 0 ? 0 : (cl > CAP ? CAP : cl);                 \
    if (t96 < cl) lsrc[sub][t96] = CSR[s0 + base + t96];                          \
    for (int j = t96; j < cl * 6; j += 96) {                                      \
      int i = j / 6, hh = j - i * 6;                                              \
      int s = CSR[s0 + base + i];                                                 \
      float e = ALS[s * 6 + hh] + ALD[n * 6 + hh];                                \
      e = e > 0.0f ? e : 0.2f * e;                                                \
      lew[sub][hh][i] = e;                                                        \
    }                                                                             \
    __syncthreads();                                                              \
    int pcl = pdeg - base; pcl = pcl < 0 ? 0 : (pcl > CAP ? CAP : pcl);           \
    float asc = 1.0f;                                                             \
    if (pcl > 0) {                                                                \
      float mc = -INFINITY;                                                       \
      for (int i = pl; i < pcl; i += 16) mc = fmaxf(mc, lew[psub][ph][i]);        \
      mc = fmaxf(mc, __shfl_xor(mc, 1));                                          \
      mc = fmaxf(mc, __shfl_xor(mc, 2));                                          \
      mc = fmaxf(mc, __shfl_xor(mc, 4));                                          \
      mc = fmaxf(mc, __shfl_xor(mc, 8));                                          \
      float mn = fmaxf(m_run, mc);                                                \
      asc = (m_run == -INFINITY) ? 0.0f : __expf(m_run - mn);                     \
      float scp = 0.0f;                                                           \
      for (int i = pl; i < pcl; i += 16) {                                        \
        float wv = __expf(lew[psub][ph][i] - mn);                                 \
        lew[psub][ph][i] = wv;                                                    \
        scp += wv;                                                                \
      }                                                                           \
      scp += __shfl_xor(scp, 1);                                                  \
      scp += __shfl_xor(scp, 2);                                                  \
      scp += __shfl_xor(scp, 4);                                                  \
      scp += __shfl_xor(scp, 8);                                                  \
      s_run = s_run * asc + scp;                                                  \
      m_run = mn;                                                                 \
    }                                                                             \
    if (pl == 0) {                                                                \
      lasc[psub][ph] = asc;                                                       \
      if (ch == nch - 1) lrr[psub][ph] = 1.0f / (s_run + 1e-16f);                 \
    }                                                                             \
    __syncthreads();                                                              \
    float cc0 = 0, cc1 = 0, cc2 = 0, cc3 = 0;                                     \
    int i = 0;                                                                    \
    for (; i + 4 <= cl; i += 4) {                                                 \
      int sA = lsrc[sub][i], sB = lsrc[sub][i + 1];                               \
      int sC = lsrc[sub][i + 2], sD = lsrc[sub][i + 3];                           \
      float wA = lew[sub][h][i], wB = lew[sub][h][i + 1];                         \
      float wC = lew[sub][h][i + 2], wD = lew[sub][h][i + 3];                     \
      f16x4 fA = *(const f16x4*)(FEAT + (size_t)sA * F_HID + c4);                 \
      f16x4 fB = *(const f16x4*)(FEAT + (size_t)sB * F_HID + c4);                 \
      f16x4 fC = *(const f16x4*)(FEAT + (size_t)sC * F_HID + c4);                 \
      f16x4 fD = *(const f16x4*)(FEAT + (size_t)sD * F_HID + c4);                 \
      cc0 += wA * (float)fA[0]; cc1 += wA * (float)fA[1];                         \
      cc2 += wA * (float)fA[2]; cc3 += wA * (float)fA[3];                         \
      cc0 += wB * (float)fB[0]; cc1 += wB * (float)fB[1];                         \
      cc2 += wB * (float)fB[2]; cc3 += wB * (float)fB[3];                         \
      cc0 += wC * (float)fC[0]; cc1 += wC * (float)fC[1];                         \
      cc2 += wC * (float)fC[2]; cc3 += wC * (float)fC[3];                         \
      cc0 += wD * (float)fD[0]; cc1 += wD * (float)fD[1];                         \
      cc2 += wD * (float)fD[2]; cc3 += wD * (float)fD[3];                         \
    }                                                                             \
    for (; i < cl; ++i) {                                                         \
      int s = lsrc[sub][i];                                                       \
      float wv = lew[sub][h][i];                                                  \
      f16x4 fv = *(const f16x4*)(FEAT + (size_t)s * F_HID + c4);                  \
      cc0 += wv * (float)fv[0]; cc1 += wv * (float)fv[1];                         \
      cc2 += wv * (float)fv[2]; cc3 += wv * (float)fv[3];                         \
    }                                                                             \
    float asc2 = lasc[sub][h];                                                    \
    a0 = a0 * asc2 + cc0; a1 = a1 * asc2 + cc1;                                   \
    a2 = a2 * asc2 + cc2; a3 = a3 * asc2 + cc3;                                   \
    __syncthreads();                                                              \
  }                                                                               \
  float rr = lrr[sub][h];

// hidden layers: normalize + bias + ELU + split-bf16 pack
__global__ __launch_bounds__(384) void agg_hidden(const _Float16* __restrict__ feat,
                                                  const int* __restrict__ off,
                                                  const int* __restrict__ csr_src,
                                                  const float* __restrict__ al_s,
                                                  const float* __restrict__ al_d,
                                                  const float* __restrict__ bias,
                                                  unsigned short* __restrict__ Apk) {
  __shared__ int   lsrc[4][CAP + 1];
  __shared__ float lew[4][6][CAP + 1];
  __shared__ float lasc[4][6];
  __shared__ float lrr[4][6];
  AGG_CORE(feat, off, csr_src, al_s, al_d)
  float v0 = a0 * rr + bias[c4 + 0];
  float v1 = a1 * rr + bias[c4 + 1];
  float v2 = a2 * rr + bias[c4 + 2];
  float v3 = a3 * rr + bias[c4 + 3];
  v0 = v0 > 0.0f ? v0 : (__expf(v0) - 1.0f);
  v1 = v1 > 0.0f ? v1 : (__expf(v1) - 1.0f);
  v2 = v2 > 0.0f ? v2 : (__expf(v2) - 1.0f);
  v3 = v3 > 0.0f ? v3 : (__expf(v3) - 1.0f);
  unsigned short h0, l0, h1, l1, h2, l2, h3, l3;
  bsplit(v0, h0, l0);
  bsplit(v1, h1, l1);
  bsplit(v2, h2, l2);
  bsplit(v3, h3, l3);
  us4 hv, lv;
  hv[0] = h0; hv[1] = h1; hv[2] = h2; hv[3] = h3;
  lv[0] = l0; lv[1] = l1; lv[2] = l2; lv[3] = l3;
  int kt = c4 >> 5, kb = (c4 >> 3) & 3, jb = (c4 & 7) * 2;
  char* basep = (char*)Apk + (size_t)n * (4 * F_HID) + kt * 128;
  int x7 = n & 7;
  *(us4*)(basep + (((2 * kb) ^ x7) << 4) + jb) = hv;
  *(us4*)(basep + (((2 * kb + 1) ^ x7) << 4) + jb) = lv;
}

// output layer: normalize + head-mean + bias
__global__ __launch_bounds__(384) void agg_out(const _Float16* __restrict__ feat,
                                               const int* __restrict__ off,
                                               const int* __restrict__ csr_src,
                                               const float* __restrict__ al_s,
                                               const float* __restrict__ al_d,
                                               const float* __restrict__ b3,
                                               float* __restrict__ out) {
  __shared__ int   lsrc[4][CAP + 1];
  __shared__ float lew[4][6][CAP + 1];
  __shared__ float lasc[4][6];
  __shared__ float lrr[4][6];
  __shared__ float red[4][384];
  AGG_CORE(feat, off, csr_src, al_s, al_d)
  red[sub][c4 + 0] = a0 * rr;
  red[sub][c4 + 1] = a1 * rr;
  red[sub][c4 + 2] = a2 * rr;
  red[sub][c4 + 3] = a3 * rr;
  __syncthreads();
  if (t96 < 16) {
    int c = t96 * 4;
    f32x4 o = (f32x4)0.0f;
#pragma unroll
    for (int hh = 0; hh < HEADS; hh++) {
#pragma unroll
      for (int j = 0; j < 4; j++) o[j] += red[sub][hh * CH + c + j];
    }
#pragma unroll
    for (int j = 0; j < 4; j++) o[j] = o[j] * (1.0f / 6.0f) + b3[c + j];
    *(f32x4*)(out + (size_t)n * CH + c) = o;
  }
}

extern "C" void kernel_launch(void* const* d_in, const int* in_sizes, int n_in,
                              void* d_out, int out_size, void* d_ws, size_t ws_size,
                              hipStream_t stream) {
  const float* x  = (const float*)d_in[0];
  const int*   ei = (const int*)d_in[1];
  const float* W_[4]  = {(const float*)d_in[2], (const float*)d_in[6],
                         (const float*)d_in[10], (const float*)d_in[14]};
  const float* AS_[4] = {(const float*)d_in[3], (const float*)d_in[7],
                         (const float*)d_in[11], (const float*)d_in[15]};
  const float* AD_[4] = {(const float*)d_in[4], (const float*)d_in[8],
                         (const float*)d_in[12], (const float*)d_in[16]};
  const float* B_[4]  = {(const float*)d_in[5], (const float*)d_in[9],
                         (const float*)d_in[13], (const float*)d_in[17]};
  float* out = (float*)d_out;

  // ---- workspace layout ----
  char* w = (char*)d_ws;
  _Float16* feat = (_Float16*)w;                  // [N,384] fp16 GEMM out
  w += (size_t)N_NODES * F_HID * 2;
  unsigned short* Apk = (unsigned short*)w;       // packed split-bf16 A (also layer-0 x)
  w += (size_t)M_PAD * 2 * F_HID * 2;
  unsigned short* Wt0 = (unsigned short*)w; w += (size_t)F_HID * 2 * K0PAD * 2;
  unsigned short* Wt1 = (unsigned short*)w; w += (size_t)F_HID * 2 * F_HID * 2;
  unsigned short* Wt2 = (unsigned short*)w; w += (size_t)F_HID * 2 * F_HID * 2;
  unsigned short* Wt3 = (unsigned short*)w; w += (size_t)F_HID * 2 * F_HID * 2;
  float* als = (float*)w; w += (size_t)N_NODES * HEADS * 4;
  float* ald = (float*)w; w += (size_t)N_NODES * HEADS * 4;
  int* off = (int*)w; w += (N_NODES + 1) * 4;
  int* cur = (int*)w; w += N_NODES * 4;
  int* deg = (int*)w; w += N_NODES * 4;
  int* csr = (int*)w;

  // ---- CSR build ----
  (void)hipMemsetAsync(deg, 0, N_NODES * sizeof(int), stream);
  count_kernel<<<cdiv(N_EDGES, 256), 256, 0, stream>>>(ei, deg);
  scan_kernel<<<1, 256, 0, stream>>>(deg, off);
  (void)hipMemcpyAsync(cur, off, N_NODES * sizeof(int), hipMemcpyDeviceToDevice, stream);
  scatter_kernel<<<cdiv(N_EDGES, 256), 256, 0, stream>>>(ei, cur, csr);

  // ---- pack inputs ----
  convert_x<<<cdiv(M_PAD * (K0PAD / 8), 256), 256, 0, stream>>>(x, Apk);
  convert_W0<<<cdiv(F_HID * (K0PAD / 8), 256), 256, 0, stream>>>(W_[0], Wt0);
  {
    dim3 g(cdiv(F_HID * (F_HID / 8), 256), 3);
    convert_W123<<<g, 256, 0, stream>>>(W_[1], W_[2], W_[3], Wt1, Wt2, Wt3);
  }
  (void)hipMemsetAsync((char*)Apk + (size_t)N_NODES * 4 * F_HID, 0,
                       (size_t)(M_PAD - N_NODES) * 4 * F_HID, stream);

  const int gemm_grid = 8 * cdiv(NBM, 8) * 3;  // XCD-grouped
  const int agg_grid = N_NODES / 4;            // 12500

  // ---- Layer 0 (K=160 packed) ----
  gemm_mfma<K0PAD><<<gemm_grid, 256, 0, stream>>>(Apk, Wt0, AS_[0], AD_[0], als, ald, feat);
  agg_hidden<<<agg_grid, 384, 0, stream>>>(feat, off, csr, als, ald, B_[0], Apk);

  // ---- Layers 1,2 (K=384) ----
  gemm_mfma<F_HID><<<gemm_grid, 256, 0, stream>>>(Apk, Wt1, AS_[1], AD_[1], als, ald, feat);
  agg_hidden<<<agg_grid, 384, 0, stream>>>(feat, off, csr, als, ald, B_[1], Apk);

  gemm_mfma<F_HID><<<gemm_grid, 256, 0, stream>>>(Apk, Wt2, AS_[2], AD_[2], als, ald, feat);
  agg_hidden<<<agg_grid, 384, 0, stream>>>(feat, off, csr, als, ald, B_[2], Apk);

  // ---- Layer 3 (K=384, mean over heads) ----
  gemm_mfma<F_HID><<<gemm_grid, 256, 0, stream>>>(Apk, Wt3, AS_[3], AD_[3], als, ald, feat);
  agg_out<<<agg_grid, 384, 0, stream>>>(feat, off, csr, als, ald, B_[3], out);
}